// Round 1
// baseline (782.323 us; speedup 1.0000x reference)
//
#include <hip/hip_runtime.h>

#define BB 8
#define NN 8192
#define NPOINT 2048
#define NSAMPLE 64
#define CIN 64
#define RADIUS 0.2f
#define R2 (RADIUS * RADIUS)

// d_out layout (flat floats, reference return order)
#define OFF_NEWXYZ 0
#define OFF_FEAT (BB * NPOINT * 3)
#define OFF_INDS (OFF_FEAT + BB * NPOINT * 128)
#define OFF_IDX (OFF_INDS + BB * NPOINT)

// ---------------------------------------------------------------------------
// Kernel 1: new_xyz gather + inds passthrough + ball query (wave per query)
// ---------------------------------------------------------------------------
__global__ __launch_bounds__(256) void ballq_kernel(
    const float* __restrict__ xyz, const int* __restrict__ inds,
    float* __restrict__ out) {
  const int wq = (blockIdx.x * 256 + threadIdx.x) >> 6;  // query id
  const int lane = threadIdx.x & 63;
  const int b = wq / NPOINT;
  const int s = wq - b * NPOINT;

  const float* xb = xyz + (size_t)b * NN * 3;
  const int ind = inds[b * NPOINT + s];
  const float cx = xb[ind * 3 + 0];
  const float cy = xb[ind * 3 + 1];
  const float cz = xb[ind * 3 + 2];

  if (lane == 0) {
    out[OFF_NEWXYZ + (size_t)wq * 3 + 0] = cx;
    out[OFF_NEWXYZ + (size_t)wq * 3 + 1] = cy;
    out[OFF_NEWXYZ + (size_t)wq * 3 + 2] = cz;
    out[OFF_INDS + wq] = (float)ind;
  }

  // match reference distance formula: qq + nn - 2*dot
  const float qq = cx * cx + cy * cy + cz * cz;
  float* myidx = out + OFF_IDX + (size_t)wq * NSAMPLE;

  int cnt = 0;
  int first = -1;
  for (int j0 = 0; j0 < NN; j0 += 64) {
    const int j = j0 + lane;
    const float px = xb[j * 3 + 0];
    const float py = xb[j * 3 + 1];
    const float pz = xb[j * 3 + 2];
    const float nn = px * px + py * py + pz * pz;
    const float dot = cx * px + cy * py + cz * pz;
    const float d2 = qq + nn - 2.0f * dot;
    const bool hit = d2 < R2;
    const unsigned long long m = __ballot(hit);
    if (hit) {
      const int pos = cnt + (int)__popcll(m & ((1ull << lane) - 1ull));
      if (pos < NSAMPLE) myidx[pos] = (float)j;
    }
    if (first < 0 && m != 0ull) first = j0 + __builtin_ctzll(m);
    cnt += (int)__popcll(m);
    if (cnt >= NSAMPLE) break;
  }
  if (first < 0) first = NN - 1;  // unreachable (query point hits itself), safe
  if (lane >= cnt) myidx[lane] = (float)first;  // pad with first hit
}

// ---------------------------------------------------------------------------
// Kernel 2: group (xyz delta + features) -> 3-layer MLP -> maxpool over samples
// Wave per query; lane = sample. Activations in registers, weights via
// wave-uniform (scalar) loads.
// ---------------------------------------------------------------------------
__global__ __launch_bounds__(256) void mlp_kernel(
    const float* __restrict__ xyz, const float* __restrict__ features,
    const int* __restrict__ inds,
    const float* __restrict__ w0, const float* __restrict__ s0,
    const float* __restrict__ t0, const float* __restrict__ w1,
    const float* __restrict__ s1, const float* __restrict__ t1,
    const float* __restrict__ w2, const float* __restrict__ s2,
    const float* __restrict__ t2, float* __restrict__ out) {
  const int wq = (blockIdx.x * 256 + threadIdx.x) >> 6;  // query id
  const int lane = threadIdx.x & 63;                     // sample id
  const int b = wq / NPOINT;
  const int s = wq - b * NPOINT;

  const float* xb = xyz + (size_t)b * NN * 3;
  const int ind = inds[b * NPOINT + s];
  const float cx = xb[ind * 3 + 0];
  const float cy = xb[ind * 3 + 1];
  const float cz = xb[ind * 3 + 2];

  const int id = (int)out[OFF_IDX + (size_t)wq * NSAMPLE + lane];

  float in[67];
  in[0] = (xb[id * 3 + 0] - cx) * (1.0f / RADIUS);
  in[1] = (xb[id * 3 + 1] - cy) * (1.0f / RADIUS);
  in[2] = (xb[id * 3 + 2] - cz) * (1.0f / RADIUS);
  const float4* frow =
      (const float4*)(features + ((size_t)b * NN + (size_t)id) * CIN);
#pragma unroll
  for (int c4 = 0; c4 < 16; ++c4) {
    const float4 f = frow[c4];
    in[3 + 4 * c4 + 0] = f.x;
    in[3 + 4 * c4 + 1] = f.y;
    in[3 + 4 * c4 + 2] = f.z;
    in[3 + 4 * c4 + 3] = f.w;
  }

  // ---- layer 0: 67 -> 64 ----
  float h0[64];
#pragma unroll
  for (int db = 0; db < 64; db += 16) {
    float acc[16];
#pragma unroll
    for (int i = 0; i < 16; ++i) acc[i] = 0.0f;
#pragma unroll
    for (int c = 0; c < 67; ++c) {
#pragma unroll
      for (int i = 0; i < 16; ++i)
        acc[i] = fmaf(in[c], w0[c * 64 + db + i], acc[i]);
    }
#pragma unroll
    for (int i = 0; i < 16; ++i)
      h0[db + i] = fmaxf(fmaf(acc[i], s0[db + i], t0[db + i]), 0.0f);
  }

  // ---- layer 1: 64 -> 64 ----
  float h1[64];
#pragma unroll
  for (int db = 0; db < 64; db += 16) {
    float acc[16];
#pragma unroll
    for (int i = 0; i < 16; ++i) acc[i] = 0.0f;
#pragma unroll
    for (int c = 0; c < 64; ++c) {
#pragma unroll
      for (int i = 0; i < 16; ++i)
        acc[i] = fmaf(h0[c], w1[c * 64 + db + i], acc[i]);
    }
#pragma unroll
    for (int i = 0; i < 16; ++i)
      h1[db + i] = fmaxf(fmaf(acc[i], s1[db + i], t1[db + i]), 0.0f);
  }

  // ---- layer 2: 64 -> 128, fused maxpool over the 64 samples (lanes) ----
  float o0 = 0.0f, o1 = 0.0f;
#pragma unroll
  for (int db = 0; db < 128; db += 16) {
    float acc[16];
#pragma unroll
    for (int i = 0; i < 16; ++i) acc[i] = 0.0f;
#pragma unroll
    for (int c = 0; c < 64; ++c) {
#pragma unroll
      for (int i = 0; i < 16; ++i)
        acc[i] = fmaf(h1[c], w2[c * 128 + db + i], acc[i]);
    }
#pragma unroll
    for (int i = 0; i < 16; ++i) {
      const int d = db + i;
      float v = fmaxf(fmaf(acc[i], s2[d], t2[d]), 0.0f);
      // wave-wide max (butterfly over 64 lanes)
#pragma unroll
      for (int off = 32; off >= 1; off >>= 1)
        v = fmaxf(v, __shfl_xor(v, off, 64));
      if ((d & 63) == lane) {
        if (d < 64)
          o0 = v;
        else
          o1 = v;
      }
    }
  }

  float* of = out + OFF_FEAT + (size_t)wq * 128;
  of[lane] = o0;
  of[64 + lane] = o1;
}

extern "C" void kernel_launch(void* const* d_in, const int* in_sizes, int n_in,
                              void* d_out, int out_size, void* d_ws,
                              size_t ws_size, hipStream_t stream) {
  const float* xyz = (const float*)d_in[0];
  const float* features = (const float*)d_in[1];
  const int* inds = (const int*)d_in[2];
  const float* w0 = (const float*)d_in[3];
  const float* s0 = (const float*)d_in[4];
  const float* t0 = (const float*)d_in[5];
  const float* w1 = (const float*)d_in[6];
  const float* s1 = (const float*)d_in[7];
  const float* t1 = (const float*)d_in[8];
  const float* w2 = (const float*)d_in[9];
  const float* s2 = (const float*)d_in[10];
  const float* t2 = (const float*)d_in[11];
  float* out = (float*)d_out;

  const int nquery = BB * NPOINT;        // 16384 queries
  const int blocks = nquery / 4;         // 4 waves (queries) per 256-thr block

  ballq_kernel<<<blocks, 256, 0, stream>>>(xyz, inds, out);
  mlp_kernel<<<blocks, 256, 0, stream>>>(xyz, features, inds, w0, s0, t0, w1,
                                         s1, t1, w2, s2, t2, out);
}